// Round 13
// baseline (96.083 us; speedup 1.0000x reference)
//
#include <hip/hip_runtime.h>
#include <hip/hip_bf16.h>
#include <cstdint>

#define NBLK 1024      // graphs
#define NPG  128       // nodes per graph
#define EPG  512       // edges per graph
#define DD   64        // feature dim
#define NSTEP 5        // MAX_STEPS + 1
#define ETOT (NBLK*EPG)
#define NEGF (-1e30f)
#define WAVES 4
#define MAXDEG 32      // P(Poisson(4) > 32) ~ 1e-19 per node; safe cap

// output element offsets (fp32 elements)
#define OA  0
#define OLS 5120
#define OPF 6144
#define OPB 11264
#define OU  16384
#define OSN 540672
#define OST 541696

struct KeysArg {
  uint32_t ke0[NSTEP], ke1[NSTEP];
  uint32_t ks0[NSTEP], ks1[NSTEP];
};

__host__ __device__ inline uint32_t rotl32(uint32_t x, int r){ return (x<<r)|(x>>(32-r)); }

// JAX threefry2x32 (20 rounds), bit-exact
__host__ __device__ inline void tf2x32(uint32_t k0, uint32_t k1, uint32_t& x0, uint32_t& x1){
  uint32_t k2 = k0 ^ k1 ^ 0x1BD11BDAu;
  x0 += k0; x1 += k1;
  x0+=x1; x1=rotl32(x1,13); x1^=x0;
  x0+=x1; x1=rotl32(x1,15); x1^=x0;
  x0+=x1; x1=rotl32(x1,26); x1^=x0;
  x0+=x1; x1=rotl32(x1, 6); x1^=x0;
  x0+=k1; x1+=k2+1u;
  x0+=x1; x1=rotl32(x1,17); x1^=x0;
  x0+=x1; x1=rotl32(x1,29); x1^=x0;
  x0+=x1; x1=rotl32(x1,16); x1^=x0;
  x0+=x1; x1=rotl32(x1,24); x1^=x0;
  x0+=k2; x1+=k0+2u;
  x0+=x1; x1=rotl32(x1,13); x1^=x0;
  x0+=x1; x1=rotl32(x1,15); x1^=x0;
  x0+=x1; x1=rotl32(x1,26); x1^=x0;
  x0+=x1; x1=rotl32(x1, 6); x1^=x0;
  x0+=k0; x1+=k1+3u;
  x0+=x1; x1=rotl32(x1,17); x1^=x0;
  x0+=x1; x1=rotl32(x1,29); x1^=x0;
  x0+=x1; x1=rotl32(x1,16); x1^=x0;
  x0+=x1; x1=rotl32(x1,24); x1^=x0;
  x0+=k1; x1+=k2+4u;
  x0+=x1; x1=rotl32(x1,13); x1^=x0;
  x0+=x1; x1=rotl32(x1,15); x1^=x0;
  x0+=x1; x1=rotl32(x1,26); x1^=x0;
  x0+=x1; x1=rotl32(x1, 6); x1^=x0;
  x0+=k2; x1+=k0+5u;
}

__device__ inline float gumbel_from_bits(uint32_t bits){
  float f = __uint_as_float((bits>>9) | 0x3f800000u) - 1.0f;
  const float tiny = 1.17549435e-38f;
  float u = fmaxf(tiny, f * (1.0f - tiny) + tiny);
  return -logf(-logf(u));
}

__device__ inline float gumbel_part(uint32_t k0, uint32_t k1, uint32_t idx){
  uint32_t x0 = 0u, x1 = idx;
  tf2x32(k0, k1, x0, x1);
  return gumbel_from_bits(x0 ^ x1);
}

__device__ inline float wsum(float x){
  #pragma unroll
  for (int off = 32; off; off >>= 1) x += __shfl_xor(x, off, 64);
  return x;
}

__device__ __forceinline__ void wsum4(float& x0, float& x1, float& x2, float& x3){
  #pragma unroll
  for (int off = 32; off; off >>= 1){
    x0 += __shfl_xor(x0, off, 64);
    x1 += __shfl_xor(x1, off, 64);
    x2 += __shfl_xor(x2, off, 64);
    x3 += __shfl_xor(x3, off, 64);
  }
}

__device__ __forceinline__ float rdlane(float v, int i){
  return __int_as_float(__builtin_amdgcn_readlane(__float_as_int(v), i));
}
__device__ __forceinline__ int rdlane_i(int v, int i){
  return __builtin_amdgcn_readlane(v, i);
}

// column matvec; 4 accs, unroll 8. Acc order identical to rounds 4-12.
__device__ __forceinline__ float matvec_col(const float* __restrict__ W, float v, int lane){
  float a0=0.f, a1=0.f, a2=0.f, a3=0.f;
  #pragma unroll 8
  for (int i = 0; i < DD; i += 4){
    a0 = fmaf(rdlane(v, i  ), W[(i  )*DD+lane], a0);
    a1 = fmaf(rdlane(v, i+1), W[(i+1)*DD+lane], a1);
    a2 = fmaf(rdlane(v, i+2), W[(i+2)*DD+lane], a2);
    a3 = fmaf(rdlane(v, i+3), W[(i+3)*DD+lane], a3);
  }
  return (a0+a1)+(a2+a3);
}

// 4-candidate batched matvec; unroll 8. Per-candidate order == matvec_col.
__device__ __forceinline__ void matvec4(const float* __restrict__ W,
                                        float v0, float v1, float v2, float v3,
                                        int lane, float o[4]){
  float acc[4][4] = {{0,0,0,0},{0,0,0,0},{0,0,0,0},{0,0,0,0}};
  #pragma unroll 8
  for (int i = 0; i < DD; i += 4){
    #pragma unroll
    for (int t = 0; t < 4; t++){
      float w  = W[(i+t)*DD+lane];
      acc[0][t] = fmaf(rdlane(v0, i+t), w, acc[0][t]);
      acc[1][t] = fmaf(rdlane(v1, i+t), w, acc[1][t]);
      acc[2][t] = fmaf(rdlane(v2, i+t), w, acc[2][t]);
      acc[3][t] = fmaf(rdlane(v3, i+t), w, acc[3][t]);
    }
  }
  #pragma unroll
  for (int c = 0; c < 4; c++)
    o[c] = (acc[c][0]+acc[c][1])+(acc[c][2]+acc[c][3]);
}

// Fat-wave schedule: every wave redundantly computes the shared dense state in
// registers (deterministic => bitwise identical). Role-split only for candidate
// scoring: waves 0,2 = backward; waves 1,3 = forward-next. Candidate scores
// cross waves via DOUBLE-BUFFERED LDS; exactly ONE barrier per step.
__global__ void __launch_bounds__(256, 4)
gfn_fused(const float* __restrict__ node_tokens,
          const float* __restrict__ edge_emb,
          const float* __restrict__ Wf1, const float* __restrict__ Wnf, const float* __restrict__ Wf2,
          const float* __restrict__ bf,  const float* __restrict__ wf,
          const float* __restrict__ Wb1, const float* __restrict__ Wnb, const float* __restrict__ Wb2,
          const float* __restrict__ bb,  const float* __restrict__ wb,
          const float* __restrict__ w_stop, const float* __restrict__ b_stop,
          const float* __restrict__ Ws,  const float* __restrict__ Wu, const float* __restrict__ bu,
          const int* __restrict__ e_src, const int* __restrict__ e_dst,
          float* __restrict__ out, KeysArg keys)
{
  const int g    = blockIdx.x;
  const int tid  = threadIdx.x;
  const int lane = tid & 63;
  const int wave = tid >> 6;
  const int ebase = g * EPG;
  const bool isBwd = (wave == 0) || (wave == 2);

  __shared__ uint8_t  srcL[EPG], dstL[EPG];
  __shared__ uint16_t listO[EPG], listI[EPG];
  __shared__ int cntO[NPG], cntI[NPG], begO[NPG], begI[NPG];
  __shared__ uint8_t usedL[EPG];
  __shared__ float xcF[2][MAXDEG];   // fwd candidate scores, double-buffered
  __shared__ float xcB[2][MAXDEG];   // bwd candidate scores, double-buffered
  __shared__ float xbb_sh[2];

  // ---- load edges, init ----
  for (int j = tid; j < EPG; j += 256){
    srcL[j] = (uint8_t)(e_src[ebase+j] - g*NPG);
    dstL[j] = (uint8_t)(e_dst[ebase+j] - g*NPG);
    usedL[j] = 0;
  }
  for (int n = tid; n < NPG; n += 256){ cntO[n]=0; cntI[n]=0; }
  __syncthreads();

  for (int j = tid; j < EPG; j += 256){
    atomicAdd(&cntO[srcL[j]], 1);
    atomicAdd(&cntI[dstL[j]], 1);
  }
  __syncthreads();

  if (wave == 0){
    int n0 = lane*2, n1 = n0+1;
    int c0O=cntO[n0], c1O=cntO[n1], sO=c0O+c1O;
    int c0I=cntI[n0], c1I=cntI[n1], sI=c0I+c1I;
    int xO=sO, xI=sI;
    #pragma unroll
    for (int off=1; off<64; off<<=1){
      int tO=__shfl_up(xO,off,64), tI=__shfl_up(xI,off,64);
      if (lane>=off){ xO+=tO; xI+=tI; }
    }
    begO[n0]=xO-sO; begO[n1]=xO-c1O;
    begI[n0]=xI-sI; begI[n1]=xI-c1I;
  }
  __syncthreads();
  for (int n = tid; n < NPG; n += 256){ cntO[n]=0; cntI[n]=0; }
  __syncthreads();

  for (int ph = 0; ph < WAVES; ph++){
    if (wave == ph){
      #pragma unroll
      for (int h = 0; h < 2; h++){
        int j = ph*128 + h*64 + lane;
        int sL = srcL[j]; int p = atomicAdd(&cntO[sL],1); listO[begO[sL]+p] = (uint16_t)j;
        int dL = dstL[j]; int q = atomicAdd(&cntI[dL],1); listI[begI[dL]+q] = (uint16_t)j;
      }
    }
    __syncthreads();
  }

  const float bf_l = bf[lane], wf_l = wf[lane];
  const float bb_l = bb[lane], wb_l = wb[lane];
  const float bu_l = bu[lane], wst_l = w_stop[lane];
  const float bstop = b_stop[0];

  // ---- hoisted per-step stop-gumbels (lane s holds step s's value) ----
  float gsv;
  {
    uint32_t k0 = keys.ks0[0], k1 = keys.ks1[0];
    #pragma unroll
    for (int s5 = 1; s5 < NSTEP; s5++)
      if (lane == s5){ k0 = keys.ks0[s5]; k1 = keys.ks1[s5]; }
    gsv = (lane < NSTEP) ? gumbel_part(k0, k1, (uint32_t)g) : 0.f;
  }

  bool done = false;
  int stepsC = 0, stopn = -1, activeL = 0;
  float lpf_sum = 0.f;
  int bOF = begO[0], dOF = min(cntO[0], MAXDEG);

  // state (per-lane register, replicated on every wave, bitwise identical)
  float st_v = 0.f;
  float acs_reg, sl_reg, gm_reg;

  // ---- prologue: step-0 dense (all waves redundant) + fwd candidates ----
  {
    float u0  = matvec_col(Wf2, st_v, lane);
    float ntv = node_tokens[(size_t)(g*NPG + 0)*DD + lane];
    float nt0 = matvec_col(Wnf, ntv, lane);
    acs_reg = matvec_col(Ws, st_v, lane);           // speculative Ws^T st
    sl_reg  = wsum(st_v * wst_l) + bstop;
    gm_reg  = (lane < dOF)
            ? gumbel_part(keys.ke0[0], keys.ke1[0], (uint32_t)(ebase + listO[bOF+lane]))
            : 0.f;
    if (!isBwd){
      for (int c = (wave==3 ? 0 : 1); c < (dOF+3)>>2; c += 2){
        int el[4]; float v[4];
        #pragma unroll
        for (int t = 0; t < 4; t++){
          int k = c*4 + t;
          el[t] = listO[bOF + min(k, dOF-1)];
          v[t]  = edge_emb[(size_t)(ebase+el[t])*DD + lane];
        }
        float o[4], x[4];
        matvec4(Wf1, v[0], v[1], v[2], v[3], lane, o);
        #pragma unroll
        for (int t = 0; t < 4; t++) x[t] = fmaxf(o[t] + nt0 + bf_l + u0, 0.f) * wf_l;
        wsum4(x[0], x[1], x[2], x[3]);
        #pragma unroll
        for (int t = 0; t < 4; t++){
          int k = c*4 + t;
          if (k < dOF && lane == 0) xcF[0][k] = usedL[el[t]] ? NEGF : x[t];
        }
      }
    }
    __syncthreads();
  }

  for (int s = 0; s < NSTEP; s++){
    const int par = s & 1;
    float act_out = -1.f, lpf_out = 0.f, lpb_out = 0.f;
    bool take_edge = false, stopped_now = false;
    int dIc = 0;

    if (!done){
      // ---- selection (redundant on all waves; xcF from LDS, rest registers) ----
      float xr = (lane < MAXDEG) ? xcF[par][lane] : NEGF;
      int   er = (lane < dOF)    ? (int)listO[bOF + lane] : -1;
      float sl = sl_reg;

      float m1 = NEGF; int nvalid = 0;
      for (int k=0;k<dOF;k++){ float xk=rdlane(xr,k); if (xk!=NEGF){ m1=fmaxf(m1,xk); nvalid++; } }
      float ex = expf(xr - m1);
      float ssum = 0.f;
      for (int k=0;k<dOF;k++){ float xk=rdlane(xr,k); if (xk!=NEGF) ssum += rdlane(ex,k); }
      const bool has_edge = nvalid > 0;
      float lse_e = m1 + logf(fmaxf(ssum, 1e-30f));
      const bool allow_stop = (stepsC < 4);
      float stop_t = allow_stop ? sl : NEGF;
      float amx = fmaxf(lse_e, stop_t);
      float Z = amx + log1pf(expf(-fabsf(lse_e - stop_t)));

      float mbest = NEGF; int elbest = -1; float xbest = 0.f;
      for (int k=0;k<dOF;k++){
        float xk = rdlane(xr,k);
        if (xk == NEGF) continue;
        float se = (xk - Z) + rdlane(gm_reg,k);
        if (se > mbest){ mbest = se; elbest = rdlane_i(er,k); xbest = xk; }
      }
      float gs = rdlane(gsv, s);
      float ss = allow_stop ? (sl - Z) + gs : NEGF;
      float mcmp = has_edge ? mbest : NEGF;
      const bool choose_stop = (ss > mcmp) || (!has_edge);
      float logp_stop = allow_stop ? (sl - Z) : 0.f;
      take_edge = !choose_stop;
      stopped_now = choose_stop;

      act_out = choose_stop ? -1.f : (float)(ebase + elbest);
      lpf_out = choose_stop ? logp_stop : (xbest - Z);
      if (choose_stop && stopn < 0) stopn = activeL;

      if (take_edge){
        const int newA = dstL[elbest];
        const bool more = (s < NSTEP-1);
        const int bI  = begI[newA]; dIc = min(cntI[newA], MAXDEG);
        const int bON = begO[newA];
        const int dON = more ? min(cntO[newA], MAXDEG) : 0;

        // ---- issue gathers early (ride under the dense block) ----
        float rv  = edge_emb[(size_t)(ebase+elbest)*DD + lane];
        float nbv = node_tokens[(size_t)(g*NPG + newA)*DD + lane];
        float vPre[4]; int elPre[4]; bool pre = false; int c0 = 0;
        if (isBwd){
          c0 = (wave==0 ? 0 : 1);
          if (c0 < ((dIc+3)>>2)){
            pre = true;
            #pragma unroll
            for (int t = 0; t < 4; t++){
              int k = c0*4 + t;
              elPre[t] = listI[bI + min(k, dIc-1)];
              vPre[t]  = edge_emb[(size_t)(ebase+elPre[t])*DD + lane];
            }
          }
        } else if (more){
          c0 = (wave==3 ? 0 : 1);
          if (c0 < ((dON+3)>>2)){
            pre = true;
            #pragma unroll
            for (int t = 0; t < 4; t++){
              int k = c0*4 + t;
              elPre[t] = listO[bON + min(k, dON-1)];
              vPre[t]  = edge_emb[(size_t)(ebase+elPre[t])*DD + lane];
            }
          }
        }

        // ---- dense block (registers only; redundant across waves) ----
        float acr = matvec_col(Wu, rv, lane);
        st_v = tanhf(acs_reg + acr + bu_l);
        float d1 = 0.f, d2 = 0.f;
        if (isBwd){
          d1 = matvec_col(Wnb, nbv, lane);            // ntb
          d2 = matvec_col(Wb2, st_v, lane);           // ub
        } else if (more){
          d1 = matvec_col(Wnf, nbv, lane);            // ntN
          d2 = matvec_col(Wf2, st_v, lane);           // uN
        }
        if (more){
          acs_reg = matvec_col(Ws, st_v, lane);       // speculative next
          sl_reg  = wsum(st_v * wst_l) + bstop;
          gm_reg  = (lane < dON)
                  ? gumbel_part(keys.ke0[s+1], keys.ke1[s+1],
                                (uint32_t)(ebase + listO[bON+lane]))
                  : 0.f;
        }
        if (tid == 0) usedL[elbest] = 1;              // for OU + steps ≥ s+2
        activeL = newA; stepsC++;

        // ---- D: candidate scoring (role-split, register dense inputs) ----
        if (isBwd){
          for (int c = c0; c < (dIc+3)>>2; c += 2){
            int el[4]; float v[4];
            if (pre && c == c0){
              #pragma unroll
              for (int t = 0; t < 4; t++){ el[t] = elPre[t]; v[t] = vPre[t]; }
            } else {
              #pragma unroll
              for (int t = 0; t < 4; t++){
                int k = c*4 + t;
                el[t] = listI[bI + min(k, dIc-1)];
                v[t]  = edge_emb[(size_t)(ebase+el[t])*DD + lane];
              }
            }
            float o[4], xb[4];
            matvec4(Wb1, v[0], v[1], v[2], v[3], lane, o);
            #pragma unroll
            for (int t = 0; t < 4; t++) xb[t] = fmaxf(o[t] + d1 + bb_l + d2, 0.f) * wb_l;
            wsum4(xb[0], xb[1], xb[2], xb[3]);
            #pragma unroll
            for (int t = 0; t < 4; t++){
              int k = c*4 + t;
              if (k < dIc && lane == 0){
                xcB[par][k] = xb[t];
                if (el[t] == elbest) xbb_sh[par] = xb[t];
              }
            }
          }
        } else if (more){
          for (int c = c0; c < (dON+3)>>2; c += 2){
            int el[4]; float v[4];
            if (pre && c == c0){
              #pragma unroll
              for (int t = 0; t < 4; t++){ el[t] = elPre[t]; v[t] = vPre[t]; }
            } else {
              #pragma unroll
              for (int t = 0; t < 4; t++){
                int k = c*4 + t;
                el[t] = listO[bON + min(k, dON-1)];
                v[t]  = edge_emb[(size_t)(ebase+el[t])*DD + lane];
              }
            }
            float o[4], x[4];
            matvec4(Wf1, v[0], v[1], v[2], v[3], lane, o);
            #pragma unroll
            for (int t = 0; t < 4; t++) x[t] = fmaxf(o[t] + d1 + bf_l + d2, 0.f) * wf_l;
            wsum4(x[0], x[1], x[2], x[3]);
            #pragma unroll
            for (int t = 0; t < 4; t++){
              int k = c*4 + t;
              if (k < dON && lane == 0)
                xcF[par^1][k] = (usedL[el[t]] || el[t] == elbest) ? NEGF : x[t];
            }
          }
        }
        bOF = bON; dOF = dON;
      }
    }

    __syncthreads();   // the ONE barrier per step (unconditional)

    if (!done && take_edge){
      // ---- bwd combine (redundant on all waves) ----
      float xbr = (lane < MAXDEG) ? xcB[par][lane] : 0.f;
      float m2 = NEGF;
      for (int k=0;k<dIc;k++) m2 = fmaxf(m2, rdlane(xbr,k));
      float ex2 = expf(xbr - m2);
      float s2 = 0.f;
      for (int k=0;k<dIc;k++) s2 += rdlane(ex2,k);
      float lse_b = m2 + logf(fmaxf(s2, 1e-30f));
      lpb_out = xbb_sh[par] - lse_b;
    }
    done = done || stopped_now;

    if (tid == 0){
      out[OA  + g*NSTEP + s] = act_out;
      out[OPF + g*NSTEP + s] = lpf_out;
      out[OPB + g*NSTEP + s] = lpb_out;
    }
    lpf_sum += lpf_out;
  }

  // ---- finalize ----
  if (tid == 0){
    out[OLS + g] = lpf_sum;
    int sn = (stopn < 0) ? activeL : stopn;
    out[OSN + g] = (float)sn;
    out[OST + g] = (float)stepsC;
  }
  for (int j = tid; j < EPG; j += 256)
    out[OU + ebase + j] = usedL[j] ? 1.0f : 0.0f;
}

extern "C" void kernel_launch(void* const* d_in, const int* in_sizes, int n_in,
                              void* d_out, int out_size, void* d_ws, size_t ws_size,
                              hipStream_t stream)
{
  (void)in_sizes; (void)n_in; (void)out_size; (void)d_ws; (void)ws_size;

  // JAX key schedule, threefry_partitionable (default since jax 0.4.36)
  KeysArg K;
  for (uint32_t s = 0; s < NSTEP; s++){
    uint32_t a = 0u, b = s;
    tf2x32(0u, 42u, a, b);
    uint32_t e0 = 0u, e1 = 0u;
    tf2x32(a, b, e0, e1);
    uint32_t s0 = 0u, s1 = 1u;
    tf2x32(a, b, s0, s1);
    K.ke0[s] = e0; K.ke1[s] = e1;
    K.ks0[s] = s0; K.ks1[s] = s1;
  }

  const int* eidx = (const int*)d_in[17];
  gfn_fused<<<dim3(NBLK), dim3(256), 0, stream>>>(
      (const float*)d_in[0],  (const float*)d_in[1],
      (const float*)d_in[2],  (const float*)d_in[3],  (const float*)d_in[4],
      (const float*)d_in[5],  (const float*)d_in[6],
      (const float*)d_in[7],  (const float*)d_in[8],  (const float*)d_in[9],
      (const float*)d_in[10], (const float*)d_in[11],
      (const float*)d_in[12], (const float*)d_in[13],
      (const float*)d_in[14], (const float*)d_in[15], (const float*)d_in[16],
      eidx, eidx + ETOT,
      (float*)d_out, K);
}

// Round 14
// 77.761 us; speedup vs baseline: 1.2356x; 1.2356x over previous
//
#include <hip/hip_runtime.h>
#include <hip/hip_bf16.h>
#include <cstdint>

#define NBLK 1024      // graphs
#define NPG  128       // nodes per graph
#define EPG  512       // edges per graph
#define DD   64        // feature dim
#define NSTEP 5        // MAX_STEPS + 1
#define ETOT (NBLK*EPG)
#define NEGF (-1e30f)
#define WAVES 4
#define MAXDEG 32      // P(Poisson(4) > 32) ~ 1e-19 per node; safe cap

// output element offsets (fp32 elements)
#define OA  0
#define OLS 5120
#define OPF 6144
#define OPB 11264
#define OU  16384
#define OSN 540672
#define OST 541696

struct KeysArg {
  uint32_t ke0[NSTEP], ke1[NSTEP];
  uint32_t ks0[NSTEP], ks1[NSTEP];
};

__host__ __device__ inline uint32_t rotl32(uint32_t x, int r){ return (x<<r)|(x>>(32-r)); }

// JAX threefry2x32 (20 rounds), bit-exact
__host__ __device__ inline void tf2x32(uint32_t k0, uint32_t k1, uint32_t& x0, uint32_t& x1){
  uint32_t k2 = k0 ^ k1 ^ 0x1BD11BDAu;
  x0 += k0; x1 += k1;
  x0+=x1; x1=rotl32(x1,13); x1^=x0;
  x0+=x1; x1=rotl32(x1,15); x1^=x0;
  x0+=x1; x1=rotl32(x1,26); x1^=x0;
  x0+=x1; x1=rotl32(x1, 6); x1^=x0;
  x0+=k1; x1+=k2+1u;
  x0+=x1; x1=rotl32(x1,17); x1^=x0;
  x0+=x1; x1=rotl32(x1,29); x1^=x0;
  x0+=x1; x1=rotl32(x1,16); x1^=x0;
  x0+=x1; x1=rotl32(x1,24); x1^=x0;
  x0+=k2; x1+=k0+2u;
  x0+=x1; x1=rotl32(x1,13); x1^=x0;
  x0+=x1; x1=rotl32(x1,15); x1^=x0;
  x0+=x1; x1=rotl32(x1,26); x1^=x0;
  x0+=x1; x1=rotl32(x1, 6); x1^=x0;
  x0+=k0; x1+=k1+3u;
  x0+=x1; x1=rotl32(x1,17); x1^=x0;
  x0+=x1; x1=rotl32(x1,29); x1^=x0;
  x0+=x1; x1=rotl32(x1,16); x1^=x0;
  x0+=x1; x1=rotl32(x1,24); x1^=x0;
  x0+=k1; x1+=k2+4u;
  x0+=x1; x1=rotl32(x1,13); x1^=x0;
  x0+=x1; x1=rotl32(x1,15); x1^=x0;
  x0+=x1; x1=rotl32(x1,26); x1^=x0;
  x0+=x1; x1=rotl32(x1, 6); x1^=x0;
  x0+=k2; x1+=k0+5u;
}

__device__ inline float gumbel_from_bits(uint32_t bits){
  float f = __uint_as_float((bits>>9) | 0x3f800000u) - 1.0f;
  const float tiny = 1.17549435e-38f;
  float u = fmaxf(tiny, f * (1.0f - tiny) + tiny);
  return -logf(-logf(u));
}

__device__ inline float gumbel_part(uint32_t k0, uint32_t k1, uint32_t idx){
  uint32_t x0 = 0u, x1 = idx;
  tf2x32(k0, k1, x0, x1);
  return gumbel_from_bits(x0 ^ x1);
}

__device__ inline float wsum(float x){
  #pragma unroll
  for (int off = 32; off; off >>= 1) x += __shfl_xor(x, off, 64);
  return x;
}

__device__ __forceinline__ void wsum4(float& x0, float& x1, float& x2, float& x3){
  #pragma unroll
  for (int off = 32; off; off >>= 1){
    x0 += __shfl_xor(x0, off, 64);
    x1 += __shfl_xor(x1, off, 64);
    x2 += __shfl_xor(x2, off, 64);
    x3 += __shfl_xor(x3, off, 64);
  }
}

__device__ __forceinline__ float rdlane(float v, int i){
  return __int_as_float(__builtin_amdgcn_readlane(__float_as_int(v), i));
}
__device__ __forceinline__ int rdlane_i(int v, int i){
  return __builtin_amdgcn_readlane(v, i);
}

// column matvec; 4 accs, unroll 8. Acc order identical to rounds 4-13.
__device__ __forceinline__ float matvec_col(const float* __restrict__ W, float v, int lane){
  float a0=0.f, a1=0.f, a2=0.f, a3=0.f;
  #pragma unroll 8
  for (int i = 0; i < DD; i += 4){
    a0 = fmaf(rdlane(v, i  ), W[(i  )*DD+lane], a0);
    a1 = fmaf(rdlane(v, i+1), W[(i+1)*DD+lane], a1);
    a2 = fmaf(rdlane(v, i+2), W[(i+2)*DD+lane], a2);
    a3 = fmaf(rdlane(v, i+3), W[(i+3)*DD+lane], a3);
  }
  return (a0+a1)+(a2+a3);
}

// 4-candidate batched matvec; unroll 8. Per-candidate order == matvec_col.
__device__ __forceinline__ void matvec4(const float* __restrict__ W,
                                        float v0, float v1, float v2, float v3,
                                        int lane, float o[4]){
  float acc[4][4] = {{0,0,0,0},{0,0,0,0},{0,0,0,0},{0,0,0,0}};
  #pragma unroll 8
  for (int i = 0; i < DD; i += 4){
    #pragma unroll
    for (int t = 0; t < 4; t++){
      float w  = W[(i+t)*DD+lane];
      acc[0][t] = fmaf(rdlane(v0, i+t), w, acc[0][t]);
      acc[1][t] = fmaf(rdlane(v1, i+t), w, acc[1][t]);
      acc[2][t] = fmaf(rdlane(v2, i+t), w, acc[2][t]);
      acc[3][t] = fmaf(rdlane(v3, i+t), w, acc[3][t]);
    }
  }
  #pragma unroll
  for (int c = 0; c < 4; c++)
    o[c] = (acc[c][0]+acc[c][1])+(acc[c][2]+acc[c][3]);
}

// R12 schedule + candidate-row forwarding: fwd-scoring waves deposit each
// candidate's edge_emb row and dst node_tokens row in LDS; Phase B reads the
// chosen one from LDS instead of a post-selection L3 gather.
__global__ void __launch_bounds__(256, 4)
gfn_fused(const float* __restrict__ node_tokens,
          const float* __restrict__ edge_emb,
          const float* __restrict__ Wf1, const float* __restrict__ Wnf, const float* __restrict__ Wf2,
          const float* __restrict__ bf,  const float* __restrict__ wf,
          const float* __restrict__ Wb1, const float* __restrict__ Wnb, const float* __restrict__ Wb2,
          const float* __restrict__ bb,  const float* __restrict__ wb,
          const float* __restrict__ w_stop, const float* __restrict__ b_stop,
          const float* __restrict__ Ws,  const float* __restrict__ Wu, const float* __restrict__ bu,
          const int* __restrict__ e_src, const int* __restrict__ e_dst,
          float* __restrict__ out, KeysArg keys)
{
  const int g    = blockIdx.x;
  const int tid  = threadIdx.x;
  const int lane = tid & 63;
  const int wave = tid >> 6;
  const int ebase = g * EPG;

  __shared__ uint8_t  srcL[EPG], dstL[EPG];
  __shared__ uint16_t listO[EPG], listI[EPG];
  __shared__ int cntO[NPG], cntI[NPG], begO[NPG], begI[NPG];
  __shared__ uint8_t usedL[EPG];
  __shared__ float st_sh[DD];
  __shared__ float u_sh[DD], nt_sh[DD], acs_sh[DD];
  __shared__ float ntb_sh[DD], ntN_sh[DD], uN_sh[DD], ubB_sh[DD];
  __shared__ float xcF[MAXDEG], gmF[MAXDEG], xcB[MAXDEG];
  __shared__ float erowF[MAXDEG][DD];   // forwarded candidate edge rows
  __shared__ float nrowF[MAXDEG][DD];   // forwarded candidate dst-node rows
  __shared__ float sl_sh, xbb_sh;

  // ---- load edges, init ----
  for (int j = tid; j < EPG; j += 256){
    srcL[j] = (uint8_t)(e_src[ebase+j] - g*NPG);
    dstL[j] = (uint8_t)(e_dst[ebase+j] - g*NPG);
    usedL[j] = 0;
  }
  for (int n = tid; n < NPG; n += 256){ cntO[n]=0; cntI[n]=0; }
  if (tid < DD) st_sh[tid] = 0.f;
  __syncthreads();

  for (int j = tid; j < EPG; j += 256){
    atomicAdd(&cntO[srcL[j]], 1);
    atomicAdd(&cntI[dstL[j]], 1);
  }
  __syncthreads();

  if (wave == 0){
    int n0 = lane*2, n1 = n0+1;
    int c0O=cntO[n0], c1O=cntO[n1], sO=c0O+c1O;
    int c0I=cntI[n0], c1I=cntI[n1], sI=c0I+c1I;
    int xO=sO, xI=sI;
    #pragma unroll
    for (int off=1; off<64; off<<=1){
      int tO=__shfl_up(xO,off,64), tI=__shfl_up(xI,off,64);
      if (lane>=off){ xO+=tO; xI+=tI; }
    }
    begO[n0]=xO-sO; begO[n1]=xO-c1O;
    begI[n0]=xI-sI; begI[n1]=xI-c1I;
  }
  __syncthreads();
  for (int n = tid; n < NPG; n += 256){ cntO[n]=0; cntI[n]=0; }
  __syncthreads();

  for (int ph = 0; ph < WAVES; ph++){
    if (wave == ph){
      #pragma unroll
      for (int h = 0; h < 2; h++){
        int j = ph*128 + h*64 + lane;
        int sL = srcL[j]; int p = atomicAdd(&cntO[sL],1); listO[begO[sL]+p] = (uint16_t)j;
        int dL = dstL[j]; int q = atomicAdd(&cntI[dL],1); listI[begI[dL]+q] = (uint16_t)j;
      }
    }
    __syncthreads();
  }

  const float bf_l = bf[lane], wf_l = wf[lane];
  const float bb_l = bb[lane], wb_l = wb[lane];
  const float bu_l = bu[lane], wst_l = w_stop[lane];
  const float bstop = b_stop[0];

  // ---- hoisted per-step stop-gumbels (lane s holds step s's value) ----
  float gsv;
  {
    uint32_t k0 = keys.ks0[0], k1 = keys.ks1[0];
    #pragma unroll
    for (int s5 = 1; s5 < NSTEP; s5++)
      if (lane == s5){ k0 = keys.ks0[s5]; k1 = keys.ks1[s5]; }
    gsv = (lane < NSTEP) ? gumbel_part(k0, k1, (uint32_t)g) : 0.f;
  }

  bool done = false;
  int stepsC = 0, stopn = -1, activeL = 0;
  float lpf_sum = 0.f;
  int bOF = begO[0], dOF = min(cntO[0], MAXDEG);

  // ---- prologue: Phase A (dense) + A2 (fwd candidates for step 0) ----
  {
    float st_v = st_sh[lane];
    if (wave == 0)      u_sh[lane]   = matvec_col(Wf2, st_v, lane);
    else if (wave == 1){ float ntv = node_tokens[(size_t)(g*NPG+0)*DD+lane];
                         nt_sh[lane] = matvec_col(Wnf, ntv, lane); }
    else if (wave == 2) acs_sh[lane] = matvec_col(Ws, st_v, lane);   // speculative
    else {
      float sl = wsum(st_v * wst_l) + bstop;
      if (lane == 0) sl_sh = sl;
      if (lane < dOF)
        gmF[lane] = gumbel_part(keys.ke0[0], keys.ke1[0], (uint32_t)(ebase + listO[bOF+lane]));
    }
    __syncthreads();
    if (wave >= 2){
      for (int c = wave-2; c < (dOF+3)>>2; c += 2){
        int el[4]; float v[4], nv[4];
        #pragma unroll
        for (int t = 0; t < 4; t++){
          int k = c*4 + t;
          el[t] = listO[bOF + min(k, dOF-1)];
          v[t]  = edge_emb[(size_t)(ebase+el[t])*DD + lane];
          nv[t] = node_tokens[(size_t)(g*NPG + dstL[el[t]])*DD + lane];
        }
        float o[4], x[4];
        matvec4(Wf1, v[0], v[1], v[2], v[3], lane, o);
        #pragma unroll
        for (int t = 0; t < 4; t++) x[t] = fmaxf(o[t] + nt_sh[lane] + bf_l + u_sh[lane], 0.f) * wf_l;
        wsum4(x[0], x[1], x[2], x[3]);
        #pragma unroll
        for (int t = 0; t < 4; t++){
          int k = c*4 + t;
          if (k < dOF){
            erowF[k][lane] = v[t];
            nrowF[k][lane] = nv[t];
            if (lane == 0) xcF[k] = usedL[el[t]] ? NEGF : x[t];
          }
        }
      }
    }
    __syncthreads();
  }

  for (int s = 0; s < NSTEP; s++){
    float act_out = -1.f, lpf_out = 0.f, lpb_out = 0.f;
    if (!done){
      // ---- selection ----
      float xr = (lane < MAXDEG) ? xcF[lane] : NEGF;
      float gr = (lane < MAXDEG) ? gmF[lane] : 0.f;
      int   er = (lane < dOF)    ? (int)listO[bOF + lane] : -1;
      float sl = sl_sh;

      float m1 = NEGF; int nvalid = 0;
      for (int k=0;k<dOF;k++){ float xk=rdlane(xr,k); if (xk!=NEGF){ m1=fmaxf(m1,xk); nvalid++; } }
      float ex = expf(xr - m1);
      float ssum = 0.f;
      for (int k=0;k<dOF;k++){ float xk=rdlane(xr,k); if (xk!=NEGF) ssum += rdlane(ex,k); }
      const bool has_edge = nvalid > 0;
      float lse_e = m1 + logf(fmaxf(ssum, 1e-30f));
      const bool allow_stop = (stepsC < 4);
      float stop_t = allow_stop ? sl : NEGF;
      float amx = fmaxf(lse_e, stop_t);
      float Z = amx + log1pf(expf(-fabsf(lse_e - stop_t)));

      float mbest = NEGF; int elbest = -1, kbest = -1; float xbest = 0.f;
      for (int k=0;k<dOF;k++){
        float xk = rdlane(xr,k);
        if (xk == NEGF) continue;
        float se = (xk - Z) + rdlane(gr,k);
        if (se > mbest){ mbest = se; elbest = rdlane_i(er,k); kbest = k; xbest = xk; }
      }
      float gs = rdlane(gsv, s);
      float ss = allow_stop ? (sl - Z) + gs : NEGF;
      float mcmp = has_edge ? mbest : NEGF;
      const bool choose_stop = (ss > mcmp) || (!has_edge);
      float logp_stop = allow_stop ? (sl - Z) : 0.f;
      const bool take_edge = !choose_stop;

      act_out = choose_stop ? -1.f : (float)(ebase + elbest);
      lpf_out = choose_stop ? logp_stop : (xbest - Z);
      if (choose_stop && stopn < 0) stopn = activeL;

      if (take_edge){
        const int newA = dstL[elbest];
        const bool more = (s < NSTEP-1);
        const int bI  = begI[newA], dIc = min(cntI[newA], MAXDEG);
        const int bON = begO[newA];
        const int dON = more ? min(cntO[newA], MAXDEG) : 0;

        // ---- PREFETCH first D-chunk edge rows (ride out through B+C) ----
        float vPre[4], nvPre[4]; int elPre[4]; bool pre = false; int c0;
        if (wave == 2 || wave == 0){
          c0 = (wave==2 ? 0 : 1);
          if (c0 < ((dIc+3)>>2)){
            pre = true;
            #pragma unroll
            for (int t = 0; t < 4; t++){
              int k = c0*4 + t;
              elPre[t] = listI[bI + min(k, dIc-1)];
              vPre[t]  = edge_emb[(size_t)(ebase+elPre[t])*DD + lane];
            }
          }
        } else {
          c0 = (wave==3 ? 0 : 1);
          if (c0 < ((dON+3)>>2)){
            pre = true;
            #pragma unroll
            for (int t = 0; t < 4; t++){
              int k = c0*4 + t;
              elPre[t] = listO[bON + min(k, dON-1)];
              vPre[t]  = edge_emb[(size_t)(ebase+elPre[t])*DD + lane];
              nvPre[t] = node_tokens[(size_t)(g*NPG + dstL[elPre[t]])*DD + lane];
            }
          }
        }

        // ---- Phase B: state' + node-token matvecs (LDS-forwarded rows) ----
        if (wave == 0){
          float rv = erowF[kbest][lane];                    // was L3 gather
          float acr = matvec_col(Wu, rv, lane);
          st_sh[lane] = tanhf(acs_sh[lane] + acr + bu_l);
          if (lane == 0) usedL[elbest] = 1;
        } else if (wave == 1){
          float nbv = nrowF[kbest][lane];                   // was L3 gather
          ntb_sh[lane] = matvec_col(Wnb, nbv, lane);
        } else if (wave == 2){
          if (more){
            float nbv = nrowF[kbest][lane];                 // was L3 gather
            ntN_sh[lane] = matvec_col(Wnf, nbv, lane);
          }
        }
        activeL = newA; stepsC++;
        __syncthreads();

        // ---- Phase C: st'-dependent matvecs + next edge-gumbels ----
        float stp = st_sh[lane];
        if (wave == 0){
          if (more) uN_sh[lane] = matvec_col(Wf2, stp, lane);
        } else if (wave == 1){
          ubB_sh[lane] = matvec_col(Wb2, stp, lane);
        } else if (wave == 2){
          if (more) acs_sh[lane] = matvec_col(Ws, stp, lane);
        } else {
          if (more){
            float s2 = wsum(stp * wst_l) + bstop;
            if (lane == 0) sl_sh = s2;
            if (lane < dON)
              gmF[lane] = gumbel_part(keys.ke0[s+1], keys.ke1[s+1],
                                      (uint32_t)(ebase + listO[bON+lane]));
          }
        }
        __syncthreads();

        // ---- Phase D ----
        if (wave == 2 || wave == 0){
          for (int c = c0; c < (dIc+3)>>2; c += 2){
            int el[4]; float v[4];
            if (pre && c == c0){
              #pragma unroll
              for (int t = 0; t < 4; t++){ el[t] = elPre[t]; v[t] = vPre[t]; }
            } else {
              #pragma unroll
              for (int t = 0; t < 4; t++){
                int k = c*4 + t;
                el[t] = listI[bI + min(k, dIc-1)];
                v[t]  = edge_emb[(size_t)(ebase+el[t])*DD + lane];
              }
            }
            float o[4], xb[4];
            matvec4(Wb1, v[0], v[1], v[2], v[3], lane, o);
            #pragma unroll
            for (int t = 0; t < 4; t++) xb[t] = fmaxf(o[t] + ntb_sh[lane] + bb_l + ubB_sh[lane], 0.f) * wb_l;
            wsum4(xb[0], xb[1], xb[2], xb[3]);
            #pragma unroll
            for (int t = 0; t < 4; t++){
              int k = c*4 + t;
              if (k < dIc && lane == 0){
                xcB[k] = xb[t];
                if (el[t] == elbest) xbb_sh = xb[t];
              }
            }
          }
        } else {
          for (int c = c0; c < (dON+3)>>2; c += 2){
            int el[4]; float v[4], nv[4];
            if (pre && c == c0){
              #pragma unroll
              for (int t = 0; t < 4; t++){ el[t] = elPre[t]; v[t] = vPre[t]; nv[t] = nvPre[t]; }
            } else {
              #pragma unroll
              for (int t = 0; t < 4; t++){
                int k = c*4 + t;
                el[t] = listO[bON + min(k, dON-1)];
                v[t]  = edge_emb[(size_t)(ebase+el[t])*DD + lane];
                nv[t] = node_tokens[(size_t)(g*NPG + dstL[el[t]])*DD + lane];
              }
            }
            float o[4], x[4];
            matvec4(Wf1, v[0], v[1], v[2], v[3], lane, o);
            #pragma unroll
            for (int t = 0; t < 4; t++) x[t] = fmaxf(o[t] + ntN_sh[lane] + bf_l + uN_sh[lane], 0.f) * wf_l;
            wsum4(x[0], x[1], x[2], x[3]);
            #pragma unroll
            for (int t = 0; t < 4; t++){
              int k = c*4 + t;
              if (k < dON){
                erowF[k][lane] = v[t];
                nrowF[k][lane] = nv[t];
                if (lane == 0) xcF[k] = usedL[el[t]] ? NEGF : x[t];
              }
            }
          }
        }
        __syncthreads();

        // ---- bwd combine (parallel exp, serial masked sum) ----
        float xbr = (lane < MAXDEG) ? xcB[lane] : 0.f;
        float m2 = NEGF;
        for (int k=0;k<dIc;k++) m2 = fmaxf(m2, rdlane(xbr,k));
        float ex2 = expf(xbr - m2);
        float s2 = 0.f;
        for (int k=0;k<dIc;k++) s2 += rdlane(ex2,k);
        float lse_b = m2 + logf(fmaxf(s2, 1e-30f));
        lpb_out = xbb_sh - lse_b;

        bOF = bON; dOF = dON;
      }
      done = done || choose_stop;
    }

    if (tid == 0){
      out[OA  + g*NSTEP + s] = act_out;
      out[OPF + g*NSTEP + s] = lpf_out;
      out[OPB + g*NSTEP + s] = lpb_out;
    }
    lpf_sum += lpf_out;
  }

  // ---- finalize ----
  if (tid == 0){
    out[OLS + g] = lpf_sum;
    int sn = (stopn < 0) ? activeL : stopn;
    out[OSN + g] = (float)sn;
    out[OST + g] = (float)stepsC;
  }
  for (int j = tid; j < EPG; j += 256)
    out[OU + ebase + j] = usedL[j] ? 1.0f : 0.0f;
}

extern "C" void kernel_launch(void* const* d_in, const int* in_sizes, int n_in,
                              void* d_out, int out_size, void* d_ws, size_t ws_size,
                              hipStream_t stream)
{
  (void)in_sizes; (void)n_in; (void)out_size; (void)d_ws; (void)ws_size;

  // JAX key schedule, threefry_partitionable (default since jax 0.4.36)
  KeysArg K;
  for (uint32_t s = 0; s < NSTEP; s++){
    uint32_t a = 0u, b = s;
    tf2x32(0u, 42u, a, b);
    uint32_t e0 = 0u, e1 = 0u;
    tf2x32(a, b, e0, e1);
    uint32_t s0 = 0u, s1 = 1u;
    tf2x32(a, b, s0, s1);
    K.ke0[s] = e0; K.ke1[s] = e1;
    K.ks0[s] = s0; K.ks1[s] = s1;
  }

  const int* eidx = (const int*)d_in[17];
  gfn_fused<<<dim3(NBLK), dim3(256), 0, stream>>>(
      (const float*)d_in[0],  (const float*)d_in[1],
      (const float*)d_in[2],  (const float*)d_in[3],  (const float*)d_in[4],
      (const float*)d_in[5],  (const float*)d_in[6],
      (const float*)d_in[7],  (const float*)d_in[8],  (const float*)d_in[9],
      (const float*)d_in[10], (const float*)d_in[11],
      (const float*)d_in[12], (const float*)d_in[13],
      (const float*)d_in[14], (const float*)d_in[15], (const float*)d_in[16],
      eidx, eidx + ETOT,
      (float*)d_out, K);
}